// Round 8
// baseline (1277.281 us; speedup 1.0000x reference)
//
#include <hip/hip_runtime.h>
#include <cstdint>
#include <cstddef>

typedef _Float16 f16;
typedef __attribute__((ext_vector_type(8))) _Float16 half8;
typedef __attribute__((ext_vector_type(4))) _Float16 half4;
typedef __attribute__((ext_vector_type(4))) float f32x4;

#define NE 50000
#define NR 400
#define DD 300
#define NTOT 50400
#define EE 800000
#define BB 2048
#define LL 32
#define HD 256
#define KP1 320
#define KP2 608

// split fp32 into fp16 hi + fp16 lo (22-bit combined mantissa)
__device__ inline void split2h(float x, f16& hi, f16& lo) {
  f16 h = (f16)x;
  hi = h;
  lo = (f16)(x - (float)h);
}

// ---------------------------------------------------------------------------
__global__ void convert_f16_kernel(const float4* __restrict__ src, half4* __restrict__ dst,
                                   int n4) {
  int i = blockIdx.x * blockDim.x + threadIdx.x;
  if (i < n4) {
    float4 v = src[i];
    dst[i] = (half4){(f16)v.x, (f16)v.y, (f16)v.z, (f16)v.w};
  }
}

__global__ void rel_proj_kernel(const float* __restrict__ r_x, const float* __restrict__ Wrel,
                                const float* __restrict__ brel, f16* __restrict__ out) {
  int row = blockIdx.x;
  int c = threadIdx.x;
  if (c >= DD) return;
  float acc = brel[c];
  const float* rr = r_x + (size_t)row * (2 * DD);
  for (int k = 0; k < 2 * DD; ++k) acc += rr[k] * Wrel[(size_t)k * DD + c];
  out[(size_t)row * DD + c] = (f16)acc;
}

__global__ void hist_kernel(const int* __restrict__ dst, int* __restrict__ counts) {
  int e = blockIdx.x * blockDim.x + threadIdx.x;
  if (e < EE) atomicAdd(&counts[dst[e]], 1);
}

__global__ __launch_bounds__(1024) void scan_kernel(const int* __restrict__ counts,
                                                    int* __restrict__ row_ptr,
                                                    int* __restrict__ cursor) {
  __shared__ int sums[1024];
  const int n = NTOT;
  int t = threadIdx.x;
  const int chunk = (n + 1023) / 1024;
  int begin = t * chunk;
  int end = begin + chunk; if (end > n) end = n;
  int s = 0;
  for (int i = begin; i < end; ++i) s += counts[i];
  sums[t] = s;
  __syncthreads();
  for (int off = 1; off < 1024; off <<= 1) {
    int v = (t >= off) ? sums[t - off] : 0;
    __syncthreads();
    sums[t] += v;
    __syncthreads();
  }
  int run = sums[t] - s;
  for (int i = begin; i < end; ++i) {
    row_ptr[i] = run; cursor[i] = run;
    run += counts[i];
  }
  if (t == 1023) row_ptr[n] = sums[1023];
}

__global__ void scatter_kernel(const int* __restrict__ dst, const int* __restrict__ src,
                               const float* __restrict__ w, int* __restrict__ cursor,
                               int* __restrict__ src_s, float* __restrict__ w_s) {
  int e = blockIdx.x * blockDim.x + threadIdx.x;
  if (e < EE) {
    int pos = atomicAdd(&cursor[dst[e]], 1);
    src_s[pos] = src[e];
    w_s[pos] = w[e];
  }
}

__global__ void detect_mask_kernel(const unsigned* __restrict__ m0, const unsigned* __restrict__ m1,
                                   const unsigned* __restrict__ m2, const unsigned* __restrict__ m3,
                                   int* __restrict__ flag) {
  int idx = blockIdx.x * blockDim.x + threadIdx.x;
  const int wp = BB * LL / 4;
  if (idx >= 4 * wp) return;
  const unsigned* p = idx < wp ? m0 : idx < 2 * wp ? m1 : idx < 3 * wp ? m2 : m3;
  if (p[idx % wp] > 1u) atomicOr(flag, 1);
}

__global__ void norm_mask4_kernel(const void* __restrict__ r0, const void* __restrict__ r1,
                                  const void* __restrict__ r2, const void* __restrict__ r3,
                                  int* __restrict__ outm, int* __restrict__ many,
                                  const int* __restrict__ flag) {
  int idx = blockIdx.x * blockDim.x + threadIdx.x;
  if (idx >= 4 * BB * LL) return;
  int mi = idx / (BB * LL), k = idx % (BB * LL);
  const void* raw = mi == 0 ? r0 : mi == 1 ? r1 : mi == 2 ? r2 : r3;
  int v = (*flag) ? (int)((const unsigned char*)raw)[k] : ((const int*)raw)[k];
  v = v ? 1 : 0;
  outm[idx] = v;
  if (v) atomicOr(&many[idx >> 5], 1);
}

__global__ void concat_ids_kernel(const int* __restrict__ a, const int* __restrict__ b,
                                  int* __restrict__ o) {
  int i = blockIdx.x * blockDim.x + threadIdx.x;
  if (i < BB) o[i] = a[i];
  else if (i < 2 * BB) o[i] = b[i - BB];
}

// aggregate: f16 gather, fp32 accumulate, split hi/lo out; pads written in-kernel
__global__ __launch_bounds__(320) void aggregate_kernel(
    const f16* __restrict__ feat, f16* __restrict__ outhi, f16* __restrict__ outlo,
    const int* __restrict__ row_ptr, const int* __restrict__ srcs, const float* __restrict__ ws) {
  int d = blockIdx.x;
  int f = threadIdx.x;
  if (f >= DD) {
    outhi[(size_t)d * KP1 + f] = (f16)0.f;
    outlo[(size_t)d * KP1 + f] = (f16)0.f;
    return;
  }
  int beg = row_ptr[d], end = row_ptr[d + 1];
  float acc = 0.f;
  int e = beg;
  for (; e + 8 <= end; e += 8) {
    int s[8]; float wv[8]; float v[8];
#pragma unroll
    for (int u = 0; u < 8; ++u) { s[u] = srcs[e + u]; wv[u] = ws[e + u]; }
#pragma unroll
    for (int u = 0; u < 8; ++u) v[u] = (float)feat[(size_t)s[u] * DD + f];
#pragma unroll
    for (int u = 0; u < 8; ++u) acc += wv[u] * v[u];
  }
  for (; e + 2 <= end; e += 2) {
    int s0 = srcs[e], s1 = srcs[e + 1];
    float w0 = ws[e], w1 = ws[e + 1];
    acc += w0 * (float)feat[(size_t)s0 * DD + f] + w1 * (float)feat[(size_t)s1 * DD + f];
  }
  if (e < end) acc += ws[e] * (float)feat[(size_t)srcs[e] * DD + f];
  f16 hi, lo; split2h(acc, hi, lo);
  outhi[(size_t)d * KP1 + f] = hi;
  outlo[(size_t)d * KP1 + f] = lo;
}

// ---- combined weight transpose+split: all matrices, one dispatch ----------
#define N_TD 11
struct TDesc {
  const float* in; f16* oh; f16* ol;
  int Kreal, Nn, Kpad, tiles_x, tile_base;
};
struct TPack { TDesc d[N_TD]; };

__global__ __launch_bounds__(256) void transpose_multi_kernel(TPack p) {
  __shared__ float tile[32][33];
  int t = blockIdx.x;
  int e = 0;
#pragma unroll
  for (int i = 1; i < N_TD; ++i)
    if (t >= p.d[i].tile_base) e = i;
  TDesc dd = p.d[e];
  int local = t - dd.tile_base;
  int k0 = (local % dd.tiles_x) * 32, n0 = (local / dd.tiles_x) * 32;
  int tx = threadIdx.x & 31, ty = threadIdx.x >> 5;
#pragma unroll
  for (int r = 0; r < 4; ++r) {
    int k = k0 + ty + r * 8, n = n0 + tx;
    float v = (k < dd.Kreal && n < dd.Nn) ? dd.in[(size_t)k * dd.Nn + n] : 0.f;
    tile[ty + r * 8][tx] = v;
  }
  __syncthreads();
#pragma unroll
  for (int r = 0; r < 4; ++r) {
    int n = n0 + ty + r * 8, k = k0 + tx;
    if (n < dd.Nn && k < dd.Kpad) {
      f16 h, l; split2h(tile[tx][ty + r * 8], h, l);
      dd.oh[(size_t)n * dd.Kpad + k] = h;
      dd.ol[(size_t)n * dd.Kpad + k] = l;
    }
  }
}

// ---------------------------------------------------------------------------
// split-fp16 MFMA GEMM, templated on NPASS (precision passes) and NT (col tiles
// per block: block computes 128 x 128*NT, reusing the A stage across tiles).
//   NPASS=1: ah*bh ; 2: + al*bh (A 22-bit, B fp16) ; 3: + ah*bl (rel ~2^-22)
// padTo: cols in [Nn, padTo) get explicit zeros (K-padding fused).
// wofuse (NT=1): route into emAll[4096 x KP2] cols dir*300..+300, zero pads.
// losfuse (NT=1): fused clamped-mean loss reduction.
// gids/g2: epilogue also writes gathered h2 rows into C cols 0..Nn-1.
// ---------------------------------------------------------------------------
template <int NPASS, int NT>
__global__ __launch_bounds__(256, 2) void mfma_gemm_kernel(
    const f16* __restrict__ Ahi, const f16* __restrict__ Alo, int lda,
    const f16* __restrict__ Bhi, const f16* __restrict__ Blo, int ldb,
    int M, int Nn, int padTo, int K, const int* __restrict__ g1,
    float* __restrict__ C, int ldc, int coloff,
    const float* __restrict__ bias, int dorelu, const int* __restrict__ rowmask,
    f16* __restrict__ Chi, f16* __restrict__ Clo, int ldc16,
    int wofuse, int losfuse, double* __restrict__ accum,
    const f16* __restrict__ g2hi, const f16* __restrict__ g2lo, const int* __restrict__ gids) {
  constexpr int BR = 128 * NT;
  __shared__ int4 sAh[512];
  __shared__ int4 sAl[(NPASS >= 2) ? 512 : 1];
  __shared__ int4 sBh[BR * 4];
  __shared__ int4 sBl[(NPASS >= 3) ? BR * 4 : 1];
  const int tid = threadIdx.x;
  const int row0 = blockIdx.y * 128, col0 = blockIdx.x * BR;
  const int wave = tid >> 6, lane = tid & 63;
  const int wrow = (wave >> 1) * 64, wcol = (wave & 1) * 64;
  const int m16 = lane & 15, quad = lane >> 4;

  const int sr = tid >> 2, sc = tid & 3;
  const f16* pah[2]; const f16* pal[2]; bool va[2]; int sidxA[2];
#pragma unroll
  for (int i = 0; i < 2; ++i) {
    int r = sr + i * 64;
    sidxA[i] = r * 4 + (sc ^ ((r >> 1) & 3));
    int grow = row0 + r;
    va[i] = grow < M;
    int ar = va[i] ? (g1 ? g1[grow] : grow) : 0;
    pah[i] = Ahi + (size_t)ar * lda + sc * 8;
    pal[i] = Alo + (size_t)ar * lda + sc * 8;
  }
  const f16* pbh[2 * NT]; const f16* pbl[2 * NT]; bool vb[2 * NT]; int sidxB[2 * NT];
#pragma unroll
  for (int i = 0; i < 2 * NT; ++i) {
    int r = sr + i * 64;
    sidxB[i] = r * 4 + (sc ^ ((r >> 1) & 3));
    int gn = col0 + r;
    vb[i] = gn < Nn;
    int br = vb[i] ? gn : 0;
    pbh[i] = Bhi + (size_t)br * ldb + sc * 8;
    pbl[i] = Blo + (size_t)br * ldb + sc * 8;
  }
  int idxA[4], idxB[4];
#pragma unroll
  for (int f = 0; f < 4; ++f) {
    int r = wrow + f * 16 + m16;
    idxA[f] = r * 4 + (quad ^ ((r >> 1) & 3));
    int n = wcol + f * 16 + m16;
    idxB[f] = n * 4 + (quad ^ ((n >> 1) & 3));
  }
  f32x4 acc[NT][4][4];
#pragma unroll
  for (int nt = 0; nt < NT; ++nt)
#pragma unroll
    for (int i = 0; i < 4; ++i)
#pragma unroll
      for (int j = 0; j < 4; ++j) acc[nt][i][j] = (f32x4){0.f, 0.f, 0.f, 0.f};

  const int4 z4 = {0, 0, 0, 0};
  for (int k0 = 0; k0 < K; k0 += 32) {
#pragma unroll
    for (int i = 0; i < 2; ++i) {
      int4 vh = z4;
      if (va[i]) vh = *(const int4*)(pah[i] + k0);
      sAh[sidxA[i]] = vh;
      if constexpr (NPASS >= 2) {
        int4 vl = z4;
        if (va[i]) vl = *(const int4*)(pal[i] + k0);
        sAl[sidxA[i]] = vl;
      }
    }
#pragma unroll
    for (int i = 0; i < 2 * NT; ++i) {
      int4 wh = z4;
      if (vb[i]) wh = *(const int4*)(pbh[i] + k0);
      sBh[sidxB[i]] = wh;
      if constexpr (NPASS >= 3) {
        int4 wl = z4;
        if (vb[i]) wl = *(const int4*)(pbl[i] + k0);
        sBl[sidxB[i]] = wl;
      }
    }
    __syncthreads();
    half8 ah[4];
#pragma unroll
    for (int f = 0; f < 4; ++f) ah[f] = *(const half8*)&sAh[idxA[f]];
#pragma unroll
    for (int nt = 0; nt < NT; ++nt) {
      half8 bh[4];
#pragma unroll
      for (int f = 0; f < 4; ++f) bh[f] = *(const half8*)&sBh[idxB[f] + nt * 512];
#pragma unroll
      for (int i = 0; i < 4; ++i)
#pragma unroll
        for (int j = 0; j < 4; ++j)
          acc[nt][i][j] = __builtin_amdgcn_mfma_f32_16x16x32_f16(ah[i], bh[j], acc[nt][i][j],
                                                                 0, 0, 0);
      if constexpr (NPASS >= 2) {
        half8 al[4];
#pragma unroll
        for (int f = 0; f < 4; ++f) al[f] = *(const half8*)&sAl[idxA[f]];
#pragma unroll
        for (int i = 0; i < 4; ++i)
#pragma unroll
          for (int j = 0; j < 4; ++j)
            acc[nt][i][j] = __builtin_amdgcn_mfma_f32_16x16x32_f16(al[i], bh[j], acc[nt][i][j],
                                                                   0, 0, 0);
      }
      if constexpr (NPASS >= 3) {
        half8 bl[4];
#pragma unroll
        for (int f = 0; f < 4; ++f) bl[f] = *(const half8*)&sBl[idxB[f] + nt * 512];
#pragma unroll
        for (int i = 0; i < 4; ++i)
#pragma unroll
          for (int j = 0; j < 4; ++j)
            acc[nt][i][j] = __builtin_amdgcn_mfma_f32_16x16x32_f16(ah[i], bl[j], acc[nt][i][j],
                                                                   0, 0, 0);
      }
    }
    __syncthreads();
  }

  if (losfuse) {
    float negs = 0.f, poss = 0.f;
#pragma unroll
    for (int i = 0; i < 4; ++i)
#pragma unroll
      for (int reg = 0; reg < 4; ++reg) {
        int row = row0 + wrow + i * 16 + quad * 4 + reg;
#pragma unroll
        for (int j = 0; j < 4; ++j) {
          int col = col0 + wcol + j * 16 + m16;
          float s = acc[0][i][j][reg];
          if (row == col) { negs += 0.2f; poss += fminf(s, 0.9f); }
          else negs += fmaxf(s, 0.2f);
        }
      }
    float* rn_ = (float*)sAh;
    float* rp_ = rn_ + 256;
    rn_[tid] = negs; rp_[tid] = poss;
    __syncthreads();
    for (int off2 = 128; off2; off2 >>= 1) {
      if (tid < off2) { rn_[tid] += rn_[tid + off2]; rp_[tid] += rp_[tid + off2]; }
      __syncthreads();
    }
    if (tid == 0) {
      atomicAdd(&accum[0], (double)rn_[0]);
      atomicAdd(&accum[1], (double)rp_[0]);
    }
    return;
  }

#pragma unroll
  for (int nt = 0; nt < NT; ++nt) {
#pragma unroll
    for (int i = 0; i < 4; ++i) {
#pragma unroll
      for (int reg = 0; reg < 4; ++reg) {
        int row = row0 + wrow + i * 16 + quad * 4 + reg;
        if (row >= M) continue;
        if (wofuse) {
          int b = row & 2047, side = (row >> 11) & 1, dir = (row >> 12) & 1;
          bool zero = rowmask[(side * 2 + dir) * BB + b] == 0;
          int orow = side * 2048 + b;
#pragma unroll
          for (int j = 0; j < 4; ++j) {
            int col = col0 + nt * 128 + wcol + j * 16 + m16;
            if (col >= padTo) continue;
            if (col >= Nn) {  // K-pad cols of emAll
              Chi[(size_t)orow * ldc16 + col] = (f16)0.f;
              Clo[(size_t)orow * ldc16 + col] = (f16)0.f;
              continue;
            }
            if ((col >= 300) != (dir != 0)) continue;
            float v = acc[nt][i][j][reg];
            if (zero) v = 0.f;
            f16 hb, lb; split2h(v, hb, lb);
            Chi[(size_t)orow * ldc16 + col] = hb;
            Clo[(size_t)orow * ldc16 + col] = lb;
          }
          continue;
        }
        bool zero = (rowmask != nullptr) && (rowmask[row] == 0);
#pragma unroll
        for (int j = 0; j < 4; ++j) {
          int col = col0 + nt * 128 + wcol + j * 16 + m16;
          if (col >= padTo) continue;
          float v = 0.f;
          if (col < Nn) {
            v = acc[nt][i][j][reg];
            if (bias) v += bias[col];
            if (dorelu) v = fmaxf(v, 0.f);
            if (zero) v = 0.f;
          }
          if (C) C[(size_t)row * ldc + coloff + col] = v;
          if (Chi) {
            f16 hb, lb; split2h(v, hb, lb);
            Chi[(size_t)row * ldc16 + coloff + col] = hb;
            if (Clo) Clo[(size_t)row * ldc16 + coloff + col] = lb;
          }
          if (gids && col < Nn) {  // fused h2 gather into C cols 0..Nn-1
            size_t go = (size_t)gids[row] * KP1 + col;
            C[(size_t)row * ldc + col] = (float)g2hi[go] + (float)g2lo[go];
          }
        }
      }
    }
  }
}

// ---------------------------------------------------------------------------
// attention over f16 kvAll[row][1024] = [k0|v0|k1|v1]; grid (BB, 4), y = dir*2+side
__global__ __launch_bounds__(256) void attention_kernel(
    const float* __restrict__ qAll, const f16* __restrict__ kv,
    const int* __restrict__ h00, const int* __restrict__ r00,
    const int* __restrict__ h01, const int* __restrict__ r01,
    const int* __restrict__ h10, const int* __restrict__ r10,
    const int* __restrict__ h11, const int* __restrict__ r11,
    const int* __restrict__ mask_norm, f16* __restrict__ ctxhi, f16* __restrict__ ctxlo) {
  int b = blockIdx.x;
  int y = blockIdx.y;
  int dir = y >> 1, side = y & 1;
  int tid = threadIdx.x;
  const int* hs = side ? (dir ? h11 : h10) : (dir ? h01 : h00);
  const int* rs = side ? (dir ? r11 : r10) : (dir ? r01 : r00);
  const int* msk = mask_norm + (size_t)(side * 2 + dir) * BB * LL;
  __shared__ float qs[256];
  __shared__ float attns[8][33];
  __shared__ int hid[32], rid[32], ms[32];
  qs[tid] = qAll[((size_t)(side * BB + b)) * 512 + dir * 256 + tid];
  if (tid < 32) {
    hid[tid] = hs[b * LL + tid];
    rid[tid] = NE + rs[b * LL + tid];
    ms[tid] = msk[b * LL + tid];
  }
  __syncthreads();
  int h = tid >> 5, l = tid & 31;
  const half8* k1 = (const half8*)(kv + (size_t)hid[l] * 1024 + dir * 512 + h * 32);
  const half8* k2 = (const half8*)(kv + (size_t)rid[l] * 1024 + dir * 512 + h * 32);
  float s = 0.f;
#pragma unroll
  for (int i = 0; i < 4; ++i) {
    half8 a = k1[i], c8 = k2[i];
    const float* qp = &qs[h * 32 + i * 8];
#pragma unroll
    for (int j = 0; j < 8; ++j) s += qp[j] * ((float)a[j] + (float)c8[j]);
  }
  s *= 0.17677669529663687f;
  s = ms[l] ? s : -1e9f;
  float m = s;
  for (int off = 16; off; off >>= 1) m = fmaxf(m, __shfl_xor(m, off, 32));
  float e = expf(s - m);
  float sum = e;
  for (int off = 16; off; off >>= 1) sum += __shfl_xor(sum, off, 32);
  attns[h][l] = e / sum;
  __syncthreads();
  int d = tid & 31;
  float c = 0.f;
#pragma unroll 4
  for (int l2 = 0; l2 < 32; ++l2) {
    float a = attns[h][l2];
    float v = (float)kv[(size_t)hid[l2] * 1024 + dir * 512 + 256 + h * 32 + d] +
              (float)kv[(size_t)rid[l2] * 1024 + dir * 512 + 256 + h * 32 + d];
    c += a * v;
  }
  f16 hb, lb; split2h(c, hb, lb);
  size_t o = ((size_t)(dir * 2 + side) * BB + b) * 256 + tid;
  ctxhi[o] = hb;
  ctxlo[o] = lb;
}

// rownorm over both lem and rem (rows contiguous in d_out), one launch
__global__ __launch_bounds__(256) void rownorm_kernel(const float* __restrict__ rows,
                                                      f16* __restrict__ outhi,
                                                      f16* __restrict__ outlo) {
  int b = blockIdx.x;
  int t = threadIdx.x;
  const float* rp = rows + (size_t)b * 600;
  float s = 0.f;
  for (int c = t; c < 600; c += 256) { float v = rp[c]; s += v * v; }
  __shared__ float red[256];
  red[t] = s;
  __syncthreads();
  for (int off = 128; off; off >>= 1) {
    if (t < off) red[t] += red[t + off];
    __syncthreads();
  }
  __shared__ float inv;
  if (t == 0) inv = 1.f / fmaxf(sqrtf(red[0]), 1e-8f);
  __syncthreads();
  for (int c = t; c < KP2; c += 256) {
    float v = (c < 600) ? rp[c] * inv : 0.f;
    f16 hb, lb; split2h(v, hb, lb);
    outhi[(size_t)b * KP2 + c] = hb;
    outlo[(size_t)b * KP2 + c] = lb;
  }
}

__global__ void finalize_kernel(const double* __restrict__ accum, float* __restrict__ out) {
  double neg = accum[0] / ((double)BB * (double)BB);
  double pos = accum[1] / (double)BB;
  out[0] = (float)(neg - 0.2 - pos + 0.9);
}

// ---------------------------------------------------------------------------
static inline void launch_mfma(hipStream_t st, int npass, int nt,
                               const f16* Ahi, const f16* Alo, int lda,
                               const f16* Bhi, const f16* Blo, int ldb, int M, int Nn, int padTo,
                               int K, const int* g1, float* C, int ldc, int coloff,
                               const float* bias, int dorelu, const int* rowmask,
                               f16* Chi, f16* Clo, int ldc16,
                               int wofuse = 0, int losfuse = 0, double* accum = nullptr,
                               const f16* g2hi = nullptr, const f16* g2lo = nullptr,
                               const int* gids = nullptr) {
  int bw = 128 * nt;
  dim3 grid((Nn + bw - 1) / bw, (M + 127) / 128);
#define ARGS Ahi, Alo, lda, Bhi, Blo, ldb, M, Nn, padTo, K, g1, C, ldc, coloff, bias, dorelu, \
             rowmask, Chi, Clo, ldc16, wofuse, losfuse, accum, g2hi, g2lo, gids
  if (nt == 2) {
    mfma_gemm_kernel<2, 2><<<grid, 256, 0, st>>>(ARGS);
  } else if (npass == 1) {
    mfma_gemm_kernel<1, 1><<<grid, 256, 0, st>>>(ARGS);
  } else if (npass == 2) {
    mfma_gemm_kernel<2, 1><<<grid, 256, 0, st>>>(ARGS);
  } else {
    mfma_gemm_kernel<3, 1><<<grid, 256, 0, st>>>(ARGS);
  }
#undef ARGS
}

extern "C" void kernel_launch(void* const* d_in, const int* in_sizes, int n_in,
                              void* d_out, int out_size, void* d_ws, size_t ws_size,
                              hipStream_t stream) {
  const float* e_x    = (const float*)d_in[0];
  const float* r_x    = (const float*)d_in[1];
  const float* edge_w = (const float*)d_in[2];
  const float* Wrel   = (const float*)d_in[3];
  const float* brel   = (const float*)d_in[4];
  const float* W1     = (const float*)d_in[5];
  const float* b1     = (const float*)d_in[6];
  const float* W2     = (const float*)d_in[7];
  const float* b2     = (const float*)d_in[8];
  const float* Wprox  = (const float*)d_in[9];
  const float* bprox  = (const float*)d_in[10];
  const float* Wq     = (const float*)d_in[11];
  const float* Wk     = (const float*)d_in[12];
  const float* Wv     = (const float*)d_in[13];
  const float* Wo     = (const float*)d_in[14];
  const int* edge_src = (const int*)d_in[15];
  const int* edge_dst = (const int*)d_in[16];
  const int* l_ids    = (const int*)d_in[17];
  const int* r_ids    = (const int*)d_in[18];
  float* out = (float*)d_out;

  // ---- workspace ----
  char* base = (char*)d_ws;
  size_t off = 0;
  auto nxt = [&](size_t bytes) -> char* {
    char* p = base + off;
    off += (bytes + 63) & ~(size_t)63;
    return p;
  };
  char* R0 = nxt(64512000);   // x f16 -> h2 f16 hi+lo (NTOT*KP1 each)
  char* R1 = nxt(64512000);   // agg f16 hi+lo -> kvAll f16 (spans into R2)
  char* R2 = nxt(60480000);   // h1 f16 -> kvAll tail
  float* qAll  = (float*)nxt(8388608);   // 4096 x 512 fp32
  f16* ctxAhi = (f16*)nxt(4194304);      // 4 x BB x 256 f16 (bytes!)
  f16* ctxAlo = (f16*)nxt(4194304);
  f16* emAhi  = (f16*)nxt(4980736);      // 4096 x KP2
  f16* emAlo  = (f16*)nxt(4980736);
  f16* lnAhi  = (f16*)nxt(4980736);      // 2*BB x KP2 (lem rows then rem rows)
  f16* lnAlo  = (f16*)nxt(4980736);
  f16* qkvhi  = (f16*)nxt(983040);       // 6 x [256 x KP1]: q0,q1,k0,v0,k1,v1
  f16* qkvlo  = (f16*)nxt(983040);
  f16* w12hi  = (f16*)nxt(384000);       // 2 x [300 x KP1]
  f16* w12lo  = (f16*)nxt(384000);
  f16* wohi   = (f16*)nxt(307200);       // [600 x 256]
  f16* wolo   = (f16*)nxt(307200);
  f16* wpxhi  = (f16*)nxt(364800);       // [300 x KP2]
  f16* wpxlo  = (f16*)nxt(364800);
  double* accum = (double*)nxt(16);
  int* row_ptr  = (int*)nxt(4 * (NTOT + 1));
  int* cursor   = (int*)nxt(4 * NTOT);
  int* counts   = (int*)nxt(4 * NTOT);
  int* src_s    = (int*)nxt(4 * EE);
  float* w_s    = (float*)nxt(4 * EE);
  int* mask_norm = (int*)nxt(4 * 4 * BB * LL);
  int* maskany   = (int*)nxt(4 * 4 * BB);
  int* idsAll    = (int*)nxt(4 * 2 * BB);
  int* flag      = (int*)nxt(64);

  f16* xbuf16 = (f16*)R0;                 // NTOT x DD
  f16* h2hi = (f16*)R0;  f16* h2lo = h2hi + (size_t)NTOT * KP1;
  f16* agghi = (f16*)R1; f16* agglo = agghi + (size_t)NTOT * KP1;
  f16* kvAll = (f16*)R1;                  // NTOT x 1024 f16, spans R1+R2
  f16* h1f16 = (f16*)R2;                  // NTOT x DD

  hipMemsetAsync(counts, 0, NTOT * sizeof(int), stream);
  hipMemsetAsync(maskany, 0, 4 * BB * sizeof(int), stream);
  hipMemsetAsync(flag, 0, sizeof(int), stream);
  hipMemsetAsync(accum, 0, 2 * sizeof(double), stream);

  // x (f16) = [e_x ; r_x @ Wrel + brel]
  convert_f16_kernel<<<(3750000 + 255) / 256, 256, 0, stream>>>((const float4*)e_x,
                                                                (half4*)xbuf16, 3750000);
  rel_proj_kernel<<<NR, 320, 0, stream>>>(r_x, Wrel, brel, xbuf16 + (size_t)NE * DD);

  // CSR
  hist_kernel<<<(EE + 255) / 256, 256, 0, stream>>>(edge_dst, counts);
  scan_kernel<<<1, 1024, 0, stream>>>(counts, row_ptr, cursor);
  scatter_kernel<<<(EE + 255) / 256, 256, 0, stream>>>(edge_dst, edge_src, edge_w, cursor, src_s,
                                                       w_s);

  // masks + ids
  detect_mask_kernel<<<256, 256, 0, stream>>>((const unsigned*)d_in[21], (const unsigned*)d_in[24],
                                              (const unsigned*)d_in[27], (const unsigned*)d_in[30],
                                              flag);
  norm_mask4_kernel<<<(4 * BB * LL + 255) / 256, 256, 0, stream>>>(
      d_in[21], d_in[24], d_in[27], d_in[30], mask_norm, maskany, flag);
  concat_ids_kernel<<<(2 * BB + 255) / 256, 256, 0, stream>>>(l_ids, r_ids, idsAll);

  // all weight transposes, one dispatch
  {
    TPack p;
    int tb = 0, idx = 0;
    auto add = [&](const float* in, f16* oh, f16* ol, int Kreal, int Nn, int Kpad) {
      int txs = (Kpad + 31) / 32, tys = (Nn + 31) / 32;
      p.d[idx] = TDesc{in, oh, ol, Kreal, Nn, Kpad, txs, tb};
      tb += txs * tys;
      ++idx;
    };
    add(Wq,             qkvhi + 0 * 81920, qkvlo + 0 * 81920, 300, 256, KP1);
    add(Wq + 300 * 256, qkvhi + 1 * 81920, qkvlo + 1 * 81920, 300, 256, KP1);
    add(Wk,             qkvhi + 2 * 81920, qkvlo + 2 * 81920, 300, 256, KP1);
    add(Wv,             qkvhi + 3 * 81920, qkvlo + 3 * 81920, 300, 256, KP1);
    add(Wk + 300 * 256, qkvhi + 4 * 81920, qkvlo + 4 * 81920, 300, 256, KP1);
    add(Wv + 300 * 256, qkvhi + 5 * 81920, qkvlo + 5 * 81920, 300, 256, KP1);
    add(W1,             w12hi,             w12lo,             300, 300, KP1);
    add(W2,             w12hi + 96000,     w12lo + 96000,     300, 300, KP1);
    add(Wo,             wohi,              wolo,              256, 300, 256);
    add(Wo + 256 * 300, wohi + 76800,      wolo + 76800,      256, 300, 256);
    add(Wprox,          wpxhi,             wpxlo,             600, 300, KP2);
    transpose_multi_kernel<<<tb, 256, 0, stream>>>(p);
  }

  // GCN (pads fused: aggregate writes agg pads; W2 epilogue writes h2 pads)
  aggregate_kernel<<<NTOT, 320, 0, stream>>>(xbuf16, agghi, agglo, row_ptr, src_s, w_s);
  launch_mfma(stream, 2, 2, agghi, agglo, KP1, w12hi, w12lo, KP1, NTOT, 300, 300, KP1, nullptr,
              nullptr, 0, 0, b1, 1, nullptr, h1f16, nullptr, 300);
  aggregate_kernel<<<NTOT, 320, 0, stream>>>(h1f16, agghi, agglo, row_ptr, src_s, w_s);
  launch_mfma(stream, 3, 1, agghi, agglo, KP1, w12hi + 96000, w12lo + 96000, KP1, NTOT, 300, KP1,
              KP1, nullptr, nullptr, 0, 0, b2, 0, nullptr, h2hi, h2lo, KP1);

  // q (batched, M=4096, N=512: dirs 0|1), fp32 out
  launch_mfma(stream, 2, 1, h2hi, h2lo, KP1, qkvhi, qkvlo, KP1, 2 * BB, 512, 512, KP1, idsAll,
              qAll, 512, 0, nullptr, 0, nullptr, nullptr, nullptr, 0);

  // kv: one fused GEMM over both dirs, N=1024 = [k0|v0|k1|v1], f16 out, NT=2
  launch_mfma(stream, 2, 2, h2hi, h2lo, KP1, qkvhi + 2 * 81920, qkvlo + 2 * 81920, KP1, NTOT,
              1024, 1024, KP1, nullptr, nullptr, 0, 0, nullptr, 0, nullptr, kvAll, nullptr, 1024);

  // attention: one launch, all 4 (dir,side) combos
  attention_kernel<<<dim3(BB, 4), 256, 0, stream>>>(
      qAll, kvAll,
      (const int*)d_in[20], (const int*)d_in[19],   // l_in
      (const int*)d_in[23], (const int*)d_in[22],   // l_out
      (const int*)d_in[26], (const int*)d_in[25],   // r_in
      (const int*)d_in[29], (const int*)d_in[28],   // r_out
      mask_norm, ctxAhi, ctxAlo);

  // Wo (batched): M=8192 over ctxAll, epilogue routes into emAll (+pad zeroing)
  launch_mfma(stream, 3, 1, ctxAhi, ctxAlo, 256, wohi, wolo, 256, 4 * BB, 600, KP2, 256, nullptr,
              nullptr, 0, 0, nullptr, 0, maskany, emAhi, emAlo, KP2, 1);

  // proximity (M=4096: lem then rem rows) with fused h2 gather into cols 0..299
  float* lem = out + 1;
  launch_mfma(stream, 3, 1, emAhi, emAlo, KP2, wpxhi, wpxlo, KP2, 4096, 300, 300, KP2, nullptr,
              lem, 600, 300, bprox, 0, nullptr, nullptr, nullptr, 0, 0, 0, nullptr, h2hi, h2lo,
              idsAll);

  // cosine similarity + fused loss
  rownorm_kernel<<<2 * BB, 256, 0, stream>>>(lem, lnAhi, lnAlo);
  launch_mfma(stream, 1, 1, lnAhi, lnAlo, KP2, lnAhi + (size_t)BB * KP2, lnAlo + (size_t)BB * KP2,
              KP2, BB, BB, BB, KP2, nullptr, nullptr, 0, 0, nullptr, 0, nullptr, nullptr, nullptr,
              0, 0, 1, accum);
  finalize_kernel<<<1, 1, 0, stream>>>(accum, out);
}